// Round 10
// baseline (153.030 us; speedup 1.0000x reference)
//
#include <hip/hip_runtime.h>

typedef float f4 __attribute__((ext_vector_type(4)));
typedef float f2 __attribute__((ext_vector_type(2)));

#define LL 64
#define BB 2048
#define DD 512
#define GB 4                 // batches per block (weight amortization x4)
#define NBLK (BB / GB)       // 512 blocks
#define DEPTH 4              // prefetch depth for x AND weights

__device__ __forceinline__ float fexp2(float x){ return __builtin_amdgcn_exp2f(x); }
__device__ __forceinline__ float frcpf_(float x){ return __builtin_amdgcn_rcpf(x); }
__device__ __forceinline__ float fsigm(float z){ return frcpf_(1.0f + fexp2(-1.442695040888963f*z)); }
__device__ __forceinline__ float ftanh_(float z){ return 1.0f - 2.0f*frcpf_(1.0f + fexp2(2.885390081777927f*z)); }

__device__ __forceinline__ f4 ld4(const float* __restrict__ p){
  return *(const f4*)p;
}
__device__ __forceinline__ f4 vexp2(f4 v){
  f4 r; r[0]=fexp2(v[0]); r[1]=fexp2(v[1]); r[2]=fexp2(v[2]); r[3]=fexp2(v[3]); return r;
}
__device__ __forceinline__ f4 vrcp(f4 v){
  f4 r; r[0]=frcpf_(v[0]); r[1]=frcpf_(v[1]); r[2]=frcpf_(v[2]); r[3]=frcpf_(v[3]); return r;
}

__global__ __launch_bounds__(128, 2) void rnn_fused_kernel(
    const float* __restrict__ x,
    const float* __restrict__ wxp, const float* __restrict__ wgp,
    const float* __restrict__ whp, const float* __restrict__ wup,
    const float* __restrict__ mp,  const float* __restrict__ fcw,
    const float* __restrict__ fcb, float* __restrict__ out)
{
  __shared__ float part[GB][LL][33];   // [g][l][quad-group], +1 pad
  const int tid = threadIdx.x;
  const int b0  = blockIdx.x;
  const int d0  = tid << 2;
  const int grp = tid >> 2;

  const f4 fw = ld4(fcw + d0);
  const f2 fwlo = __builtin_shufflevector(fw, fw, 0, 1);
  const f2 fwhi = __builtin_shufflevector(fw, fw, 2, 3);
  const size_t PL = (size_t)BB * DD;

  // consecutive batches: block handles b = b0*GB .. b0*GB+GB-1
  const float* xbase[GB];
  #pragma unroll
  for (int g = 0; g < GB; ++g)
    xbase[g] = x + (size_t)(b0 * GB + g) * DD + d0;

  // ---- deep prefetch rings: x[1..DEPTH] and weights[1..DEPTH]
  f4 xq[GB][DEPTH];
  f4 wxq[DEPTH], wgq[DEPTH], whq[DEPTH], wuq[DEPTH], mmq[DEPTH];
  #pragma unroll
  for (int k = 0; k < DEPTH; ++k){
    const int s = 1 + k;
    #pragma unroll
    for (int g = 0; g < GB; ++g)
      xq[g][k] = ld4(xbase[g] + (size_t)s * PL);
    wxq[k] = ld4(wxp + s * DD + d0);
    wgq[k] = ld4(wgp + s * DD + d0);
    whq[k] = ld4(whp + s * DD + d0);
    wuq[k] = ld4(wup + s * DD + d0);
    mmq[k] = ld4(mp  + s * DD + d0);
  }

  // ---- t = 0
  f4 w0x = ld4(wxp + d0);
  f4 w0g = ld4(wgp + d0);
  f4 h0v[GB], h[GB], xb[GB];
  #pragma unroll
  for (int g = 0; g < GB; ++g){
    f4 x0 = ld4(xbase[g]);
    float c0 = x0[0]*fw[0] + x0[1]*fw[1] + x0[2]*fw[2] + x0[3]*fw[3];
    c0 += __shfl_xor(c0, 1);
    c0 += __shfl_xor(c0, 2);
    if ((tid & 3) == 0) part[g][0][grp] = c0;

    float c1 = 0.0f;
    #pragma unroll
    for (int j = 0; j < 4; ++j){
      h0v[g][j] = ftanh_(x0[j] * w0x[j]);
      xb[g][j]  = h0v[g][j] * w0g[j] + x0[j];
      c1       += xb[g][j] * fw[j];
    }
    h[g] = h0v[g];
    c1 += __shfl_xor(c1, 1);
    c1 += __shfl_xor(c1, 2);
    if ((tid & 3) == 0) part[g][1][grp] = c1;
  }

  // ---- main scan: t = 1..62 (x[63]/w[63] never used); unroll 4 -> ring
  //      rotation becomes register renaming
  #pragma unroll 4
  for (int t = 1; t < LL - 1; ++t){
    const int tpn = (t + DEPTH <= LL - 2) ? (t + DEPTH) : (LL - 2);
    // issue ALL next-step loads first (consumed DEPTH iters from now)
    f4 xC[GB];
    #pragma unroll
    for (int g = 0; g < GB; ++g)
      xC[g] = ld4(xbase[g] + (size_t)tpn * PL);
    f4 wxn = ld4(wxp + tpn * DD + d0);
    f4 wgn = ld4(wgp + tpn * DD + d0);
    f4 whn = ld4(whp + tpn * DD + d0);
    f4 wun = ld4(wup + tpn * DD + d0);
    f4 mmn = ld4(mp  + tpn * DD + d0);

    // consume ring fronts (loaded DEPTH iters ago)
    f4 wxs = wxq[0] * 2.885390081777927f;
    f4 whs = whq[0] * -1.442695040888963f;
    f4 wus = wuq[0] * -1.442695040888963f;
    f4 wgc = wgq[0];
    f4 mmc = mmq[0];

    #pragma unroll
    for (int g = 0; g < GB; ++g){
      f4 xtr  = xb[g] + mmc * (xq[g][0] - xb[g]);
      f4 u    = 1.0f - 2.0f * vrcp(1.0f + vexp2(xtr * wxs));
      f4 sarg = h[g] * whs + u * wus;
      f4 ff   = vrcp(1.0f + vexp2(sarg)) * mmc;
      f4 mn   = __builtin_elementwise_min(1.0f - ff, u);
      f4 hn   = ff * h[g] + mn;
      hn      = __builtin_elementwise_max(hn, h0v[g]);
      h[g]  = hn;
      xb[g] = hn * wgc + xtr;

      f2 c2 = __builtin_shufflevector(xb[g], xb[g], 0, 1) * fwlo
            + __builtin_shufflevector(xb[g], xb[g], 2, 3) * fwhi;
      float cc = c2[0] + c2[1];
      cc += __shfl_xor(cc, 1);
      cc += __shfl_xor(cc, 2);
      if ((tid & 3) == 0) part[g][t + 1][grp] = cc;

      #pragma unroll
      for (int k = 0; k < DEPTH - 1; ++k) xq[g][k] = xq[g][k + 1];
      xq[g][DEPTH - 1] = xC[g];
    }

    #pragma unroll
    for (int k = 0; k < DEPTH - 1; ++k){
      wxq[k] = wxq[k + 1]; wgq[k] = wgq[k + 1]; whq[k] = whq[k + 1];
      wuq[k] = wuq[k + 1]; mmq[k] = mmq[k + 1];
    }
    wxq[DEPTH - 1] = wxn; wgq[DEPTH - 1] = wgn; whq[DEPTH - 1] = whn;
    wuq[DEPTH - 1] = wun; mmq[DEPTH - 1] = mmn;
  }

  __syncthreads();

  // ---- epilogue: GB*LL = 256 outputs, 128 threads -> 2 rounds
  #pragma unroll
  for (int rep = 0; rep < (GB * LL) / 128; ++rep){
    const int idx = tid + rep * 128;
    const int l = idx & 63;
    const int g = idx >> 6;
    float s = 0.0f;
    #pragma unroll
    for (int j = 0; j < 32; ++j) s += part[g][l][j];
    out[(size_t)l * BB + (b0 * GB + g)] = fsigm(s + fcb[0]);
  }
}

extern "C" void kernel_launch(void* const* d_in, const int* in_sizes, int n_in,
                              void* d_out, int out_size, void* d_ws, size_t ws_size,
                              hipStream_t stream)
{
  const float* x   = (const float*)d_in[0];
  const float* wx  = (const float*)d_in[1];
  const float* wg  = (const float*)d_in[2];
  const float* wh  = (const float*)d_in[3];
  const float* wu  = (const float*)d_in[4];
  const float* m   = (const float*)d_in[5];
  const float* fcw = (const float*)d_in[6];
  const float* fcb = (const float*)d_in[7];
  float* out = (float*)d_out;
  rnn_fused_kernel<<<dim3(NBLK), dim3(128), 0, stream>>>(x, wx, wg, wh, wu, m, fcw, fcb, out);
}

// Round 11
// 57.175 us; speedup vs baseline: 2.6765x; 2.6765x over previous
//
#include <hip/hip_runtime.h>

typedef float f4 __attribute__((ext_vector_type(4)));
typedef float f2 __attribute__((ext_vector_type(2)));

#define LL 64
#define BB 2048
#define DD 512
#define GB 2                 // batches per block (consecutive)
#define NBLK (BB / GB)       // 1024 blocks
#define DEPTH 4              // prefetch depth for x AND weights

__device__ __forceinline__ float fexp2(float x){ return __builtin_amdgcn_exp2f(x); }
__device__ __forceinline__ float frcpf_(float x){ return __builtin_amdgcn_rcpf(x); }
__device__ __forceinline__ float fsigm(float z){ return frcpf_(1.0f + fexp2(-1.442695040888963f*z)); }
__device__ __forceinline__ float ftanh_(float z){ return 1.0f - 2.0f*frcpf_(1.0f + fexp2(2.885390081777927f*z)); }

__device__ __forceinline__ f4 ld4(const float* __restrict__ p){
  return *(const f4*)p;
}
__device__ __forceinline__ f4 vexp2(f4 v){
  f4 r; r[0]=fexp2(v[0]); r[1]=fexp2(v[1]); r[2]=fexp2(v[2]); r[3]=fexp2(v[3]); return r;
}
__device__ __forceinline__ f4 vrcp(f4 v){
  f4 r; r[0]=frcpf_(v[0]); r[1]=frcpf_(v[1]); r[2]=frcpf_(v[2]); r[3]=frcpf_(v[3]); return r;
}

// launch_bounds (128,1): do NOT cap VGPRs at 128 — R10 proved (128,2) caps the
// allocator at 128 and the DEPTH-4 rings then spill to scratch.
__global__ __launch_bounds__(128, 1) void rnn_fused_kernel(
    const float* __restrict__ x,
    const float* __restrict__ wxp, const float* __restrict__ wgp,
    const float* __restrict__ whp, const float* __restrict__ wup,
    const float* __restrict__ mp,  const float* __restrict__ fcw,
    const float* __restrict__ fcb, float* __restrict__ out)
{
  __shared__ float part[GB][LL][33];   // [g][l][quad-group], +1 pad
  const int tid = threadIdx.x;
  const int b0  = blockIdx.x;
  const int d0  = tid << 2;
  const int grp = tid >> 2;

  const f4 fw = ld4(fcw + d0);
  const f2 fwlo = __builtin_shufflevector(fw, fw, 0, 1);
  const f2 fwhi = __builtin_shufflevector(fw, fw, 2, 3);
  const size_t PL = (size_t)BB * DD;

  // consecutive batches: block handles b = b0*GB .. b0*GB+GB-1
  const float* xbase[GB];
  #pragma unroll
  for (int g = 0; g < GB; ++g)
    xbase[g] = x + (size_t)(b0 * GB + g) * DD + d0;

  // ---- deep prefetch rings: x[1..DEPTH] and weights[1..DEPTH]
  f4 xq[GB][DEPTH];
  f4 wxq[DEPTH], wgq[DEPTH], whq[DEPTH], wuq[DEPTH], mmq[DEPTH];
  #pragma unroll
  for (int k = 0; k < DEPTH; ++k){
    const int s = 1 + k;
    #pragma unroll
    for (int g = 0; g < GB; ++g)
      xq[g][k] = ld4(xbase[g] + (size_t)s * PL);
    wxq[k] = ld4(wxp + s * DD + d0);
    wgq[k] = ld4(wgp + s * DD + d0);
    whq[k] = ld4(whp + s * DD + d0);
    wuq[k] = ld4(wup + s * DD + d0);
    mmq[k] = ld4(mp  + s * DD + d0);
  }

  // ---- t = 0
  f4 w0x = ld4(wxp + d0);
  f4 w0g = ld4(wgp + d0);
  f4 h0v[GB], h[GB], xb[GB];
  #pragma unroll
  for (int g = 0; g < GB; ++g){
    f4 x0 = ld4(xbase[g]);
    float c0 = x0[0]*fw[0] + x0[1]*fw[1] + x0[2]*fw[2] + x0[3]*fw[3];
    c0 += __shfl_xor(c0, 1);
    c0 += __shfl_xor(c0, 2);
    if ((tid & 3) == 0) part[g][0][grp] = c0;

    float c1 = 0.0f;
    #pragma unroll
    for (int j = 0; j < 4; ++j){
      h0v[g][j] = ftanh_(x0[j] * w0x[j]);
      xb[g][j]  = h0v[g][j] * w0g[j] + x0[j];
      c1       += xb[g][j] * fw[j];
    }
    h[g] = h0v[g];
    c1 += __shfl_xor(c1, 1);
    c1 += __shfl_xor(c1, 2);
    if ((tid & 3) == 0) part[g][1][grp] = c1;
  }

  // ---- main scan: t = 1..62 (x[63]/w[63] never used); unroll 4 -> ring
  //      rotation becomes register renaming
  #pragma unroll 4
  for (int t = 1; t < LL - 1; ++t){
    const int tpn = (t + DEPTH <= LL - 2) ? (t + DEPTH) : (LL - 2);
    // issue ALL next-step loads first (consumed DEPTH iters from now)
    f4 xC[GB];
    #pragma unroll
    for (int g = 0; g < GB; ++g)
      xC[g] = ld4(xbase[g] + (size_t)tpn * PL);
    f4 wxn = ld4(wxp + tpn * DD + d0);
    f4 wgn = ld4(wgp + tpn * DD + d0);
    f4 whn = ld4(whp + tpn * DD + d0);
    f4 wun = ld4(wup + tpn * DD + d0);
    f4 mmn = ld4(mp  + tpn * DD + d0);

    // consume ring fronts (loaded DEPTH iters ago)
    f4 wxs = wxq[0] * 2.885390081777927f;
    f4 whs = whq[0] * -1.442695040888963f;
    f4 wus = wuq[0] * -1.442695040888963f;
    f4 wgc = wgq[0];
    f4 mmc = mmq[0];

    #pragma unroll
    for (int g = 0; g < GB; ++g){
      f4 xtr  = xb[g] + mmc * (xq[g][0] - xb[g]);
      f4 u    = 1.0f - 2.0f * vrcp(1.0f + vexp2(xtr * wxs));
      f4 sarg = h[g] * whs + u * wus;
      f4 ff   = vrcp(1.0f + vexp2(sarg)) * mmc;
      f4 mn   = __builtin_elementwise_min(1.0f - ff, u);
      f4 hn   = ff * h[g] + mn;
      hn      = __builtin_elementwise_max(hn, h0v[g]);
      h[g]  = hn;
      xb[g] = hn * wgc + xtr;

      f2 c2 = __builtin_shufflevector(xb[g], xb[g], 0, 1) * fwlo
            + __builtin_shufflevector(xb[g], xb[g], 2, 3) * fwhi;
      float cc = c2[0] + c2[1];
      cc += __shfl_xor(cc, 1);
      cc += __shfl_xor(cc, 2);
      if ((tid & 3) == 0) part[g][t + 1][grp] = cc;

      #pragma unroll
      for (int k = 0; k < DEPTH - 1; ++k) xq[g][k] = xq[g][k + 1];
      xq[g][DEPTH - 1] = xC[g];
    }

    #pragma unroll
    for (int k = 0; k < DEPTH - 1; ++k){
      wxq[k] = wxq[k + 1]; wgq[k] = wgq[k + 1]; whq[k] = whq[k + 1];
      wuq[k] = wuq[k + 1]; mmq[k] = mmq[k + 1];
    }
    wxq[DEPTH - 1] = wxn; wgq[DEPTH - 1] = wgn; whq[DEPTH - 1] = whn;
    wuq[DEPTH - 1] = wun; mmq[DEPTH - 1] = mmn;
  }

  __syncthreads();

  // ---- epilogue: 128 threads = 2 batches x 64 l-rows
  {
    const int l = tid & 63;
    const int g = tid >> 6;
    float s = 0.0f;
    #pragma unroll
    for (int j = 0; j < 32; ++j) s += part[g][l][j];
    out[(size_t)l * BB + (b0 * GB + g)] = fsigm(s + fcb[0]);
  }
}

extern "C" void kernel_launch(void* const* d_in, const int* in_sizes, int n_in,
                              void* d_out, int out_size, void* d_ws, size_t ws_size,
                              hipStream_t stream)
{
  const float* x   = (const float*)d_in[0];
  const float* wx  = (const float*)d_in[1];
  const float* wg  = (const float*)d_in[2];
  const float* wh  = (const float*)d_in[3];
  const float* wu  = (const float*)d_in[4];
  const float* m   = (const float*)d_in[5];
  const float* fcw = (const float*)d_in[6];
  const float* fcb = (const float*)d_in[7];
  float* out = (float*)d_out;
  rnn_fused_kernel<<<dim3(NBLK), dim3(128), 0, stream>>>(x, wx, wg, wh, wu, m, fcw, fcb, out);
}

// Round 12
// 52.399 us; speedup vs baseline: 2.9205x; 1.0911x over previous
//
#include <hip/hip_runtime.h>

typedef float f4 __attribute__((ext_vector_type(4)));
typedef float f2 __attribute__((ext_vector_type(2)));

#define LL 64
#define BB 2048
#define DD 512
#define GB 2                 // batches per block (consecutive)
#define NBLK (BB / GB)       // 1024 blocks
#define DEPTH 4              // prefetch depth for x AND weights

__device__ __forceinline__ float fexp2(float x){ return __builtin_amdgcn_exp2f(x); }
__device__ __forceinline__ float frcpf_(float x){ return __builtin_amdgcn_rcpf(x); }
__device__ __forceinline__ float fsigm(float z){ return frcpf_(1.0f + fexp2(-1.442695040888963f*z)); }
__device__ __forceinline__ float ftanh_(float z){ return 1.0f - 2.0f*frcpf_(1.0f + fexp2(2.885390081777927f*z)); }

__device__ __forceinline__ f4 ld4(const float* __restrict__ p){
  return *(const f4*)p;
}
__device__ __forceinline__ f4 vexp2(f4 v){
  f4 r; r[0]=fexp2(v[0]); r[1]=fexp2(v[1]); r[2]=fexp2(v[2]); r[3]=fexp2(v[3]); return r;
}
__device__ __forceinline__ f4 vrcp(f4 v){
  f4 r; r[0]=frcpf_(v[0]); r[1]=frcpf_(v[1]); r[2]=frcpf_(v[2]); r[3]=frcpf_(v[3]); return r;
}

// Quad reduction via DPP quad_perm adds: pure VALU (2 ops), no DS pipe, no
// ~120cy ds_swizzle round-trips in the per-iteration dependency chain.
__device__ __forceinline__ float quad_reduce_dpp(float v){
  int t1 = __builtin_amdgcn_update_dpp(0, __builtin_bit_cast(int, v),
                                       0xB1 /*quad_perm [1,0,3,2]*/, 0xF, 0xF, true);
  v += __builtin_bit_cast(float, t1);
  int t2 = __builtin_amdgcn_update_dpp(0, __builtin_bit_cast(int, v),
                                       0x4E /*quad_perm [2,3,0,1]*/, 0xF, 0xF, true);
  v += __builtin_bit_cast(float, t2);
  return v;
}

// (128,1): no VGPR cap (R10: (128,2) capped at 128 and spilled the rings)
__global__ __launch_bounds__(128, 1) void rnn_fused_kernel(
    const float* __restrict__ x,
    const float* __restrict__ wxp, const float* __restrict__ wgp,
    const float* __restrict__ whp, const float* __restrict__ wup,
    const float* __restrict__ mp,  const float* __restrict__ fcw,
    const float* __restrict__ fcb, float* __restrict__ out)
{
  __shared__ float part[GB][LL][33];   // [g][l][quad-group], +1 pad
  const int tid = threadIdx.x;
  const int b0  = blockIdx.x;
  const int d0  = tid << 2;
  const int grp = tid >> 2;

  const f4 fw = ld4(fcw + d0);
  const f2 fwlo = __builtin_shufflevector(fw, fw, 0, 1);
  const f2 fwhi = __builtin_shufflevector(fw, fw, 2, 3);
  const size_t PL = (size_t)BB * DD;

  // consecutive batches: block handles b = b0*GB .. b0*GB+GB-1
  const float* xbase[GB];
  #pragma unroll
  for (int g = 0; g < GB; ++g)
    xbase[g] = x + (size_t)(b0 * GB + g) * DD + d0;

  // ---- deep prefetch rings: x[1..DEPTH] and weights[1..DEPTH]
  f4 xq[GB][DEPTH];
  f4 wxq[DEPTH], wgq[DEPTH], whq[DEPTH], wuq[DEPTH], mmq[DEPTH];
  #pragma unroll
  for (int k = 0; k < DEPTH; ++k){
    const int s = 1 + k;
    #pragma unroll
    for (int g = 0; g < GB; ++g)
      xq[g][k] = ld4(xbase[g] + (size_t)s * PL);
    wxq[k] = ld4(wxp + s * DD + d0);
    wgq[k] = ld4(wgp + s * DD + d0);
    whq[k] = ld4(whp + s * DD + d0);
    wuq[k] = ld4(wup + s * DD + d0);
    mmq[k] = ld4(mp  + s * DD + d0);
  }

  // ---- t = 0
  f4 w0x = ld4(wxp + d0);
  f4 w0g = ld4(wgp + d0);
  f4 h0v[GB], h[GB], xb[GB];
  #pragma unroll
  for (int g = 0; g < GB; ++g){
    f4 x0 = ld4(xbase[g]);
    float c0 = quad_reduce_dpp(x0[0]*fw[0] + x0[1]*fw[1] + x0[2]*fw[2] + x0[3]*fw[3]);
    if ((tid & 3) == 0) part[g][0][grp] = c0;

    float c1 = 0.0f;
    #pragma unroll
    for (int j = 0; j < 4; ++j){
      h0v[g][j] = ftanh_(x0[j] * w0x[j]);
      xb[g][j]  = h0v[g][j] * w0g[j] + x0[j];
      c1       += xb[g][j] * fw[j];
    }
    h[g] = h0v[g];
    c1 = quad_reduce_dpp(c1);
    if ((tid & 3) == 0) part[g][1][grp] = c1;
  }

  // ---- main scan: t = 1..62 (x[63]/w[63] never used); unroll 4 -> ring
  //      rotation becomes register renaming
  #pragma unroll 4
  for (int t = 1; t < LL - 1; ++t){
    const int tpn = (t + DEPTH <= LL - 2) ? (t + DEPTH) : (LL - 2);
    // issue ALL next-step loads first (consumed DEPTH iters from now)
    f4 xC[GB];
    #pragma unroll
    for (int g = 0; g < GB; ++g)
      xC[g] = ld4(xbase[g] + (size_t)tpn * PL);
    f4 wxn = ld4(wxp + tpn * DD + d0);
    f4 wgn = ld4(wgp + tpn * DD + d0);
    f4 whn = ld4(whp + tpn * DD + d0);
    f4 wun = ld4(wup + tpn * DD + d0);
    f4 mmn = ld4(mp  + tpn * DD + d0);

    // consume ring fronts (loaded DEPTH iters ago)
    f4 wxs = wxq[0] * 2.885390081777927f;
    f4 whs = whq[0] * -1.442695040888963f;
    f4 wus = wuq[0] * -1.442695040888963f;
    f4 wgc = wgq[0];
    f4 mmc = mmq[0];

    #pragma unroll
    for (int g = 0; g < GB; ++g){
      f4 xtr  = xb[g] + mmc * (xq[g][0] - xb[g]);
      f4 u    = 1.0f - 2.0f * vrcp(1.0f + vexp2(xtr * wxs));
      f4 sarg = h[g] * whs + u * wus;
      f4 ff   = vrcp(1.0f + vexp2(sarg)) * mmc;
      f4 mn   = __builtin_elementwise_min(1.0f - ff, u);
      f4 hn   = ff * h[g] + mn;
      hn      = __builtin_elementwise_max(hn, h0v[g]);
      h[g]  = hn;
      xb[g] = hn * wgc + xtr;

      f2 c2 = __builtin_shufflevector(xb[g], xb[g], 0, 1) * fwlo
            + __builtin_shufflevector(xb[g], xb[g], 2, 3) * fwhi;
      float cc = quad_reduce_dpp(c2[0] + c2[1]);
      if ((tid & 3) == 0) part[g][t + 1][grp] = cc;

      #pragma unroll
      for (int k = 0; k < DEPTH - 1; ++k) xq[g][k] = xq[g][k + 1];
      xq[g][DEPTH - 1] = xC[g];
    }

    #pragma unroll
    for (int k = 0; k < DEPTH - 1; ++k){
      wxq[k] = wxq[k + 1]; wgq[k] = wgq[k + 1]; whq[k] = whq[k + 1];
      wuq[k] = wuq[k + 1]; mmq[k] = mmq[k + 1];
    }
    wxq[DEPTH - 1] = wxn; wgq[DEPTH - 1] = wgn; whq[DEPTH - 1] = whn;
    wuq[DEPTH - 1] = wun; mmq[DEPTH - 1] = mmn;
  }

  __syncthreads();

  // ---- epilogue: 128 threads = 2 batches x 64 l-rows
  {
    const int l = tid & 63;
    const int g = tid >> 6;
    float s = 0.0f;
    #pragma unroll
    for (int j = 0; j < 32; ++j) s += part[g][l][j];
    out[(size_t)l * BB + (b0 * GB + g)] = fsigm(s + fcb[0]);
  }
}

extern "C" void kernel_launch(void* const* d_in, const int* in_sizes, int n_in,
                              void* d_out, int out_size, void* d_ws, size_t ws_size,
                              hipStream_t stream)
{
  const float* x   = (const float*)d_in[0];
  const float* wx  = (const float*)d_in[1];
  const float* wg  = (const float*)d_in[2];
  const float* wh  = (const float*)d_in[3];
  const float* wu  = (const float*)d_in[4];
  const float* m   = (const float*)d_in[5];
  const float* fcw = (const float*)d_in[6];
  const float* fcb = (const float*)d_in[7];
  float* out = (float*)d_out;
  rnn_fused_kernel<<<dim3(NBLK), dim3(128), 0, stream>>>(x, wx, wg, wh, wu, m, fcw, fcb, out);
}